// Round 6
// baseline (285.519 us; speedup 1.0000x reference)
//
#include <hip/hip_runtime.h>
#include <math.h>

#define BATCH  2
#define SEQ    2048
#define DMODEL 1024
#define NH     16
#define HD     64
#define NQKV   3072
#define ROWS   (BATCH*SEQ)
#define NT     (SEQ/128)
#define QSCALE 0.18033688f   // 0.125 * log2(e): QK^T scores land in log2 domain

typedef unsigned short u16;
typedef unsigned int   u32;
typedef __bf16 bf16x8 __attribute__((ext_vector_type(8)));
typedef float  f32x4  __attribute__((ext_vector_type(4)));

typedef const __attribute__((address_space(1))) void* gptr_t;
typedef __attribute__((address_space(3))) void* lptr_t;

__device__ __forceinline__ void gload16(lptr_t l, const void* g) {
    __builtin_amdgcn_global_load_lds((gptr_t)g, l, 16, 0, 0);
}

__device__ __forceinline__ u16 f2bf(float f) {          // RNE f32->bf16
    unsigned int u = __float_as_uint(f);
    u += 0x7FFFu + ((u >> 16) & 1u);
    return (u16)(u >> 16);
}
__device__ __forceinline__ u32 pk2(float lo, float hi) { // pack 2 f32 -> 2 bf16
#if __has_builtin(__builtin_amdgcn_cvt_pk_bf16_f32)
    typedef __bf16 bf16x2 __attribute__((ext_vector_type(2)));
    union { bf16x2 v; u32 u; } cv;
    cv.v = __builtin_amdgcn_cvt_pk_bf16_f32(lo, hi);
    return cv.u;
#else
    return (u32)f2bf(lo) | ((u32)f2bf(hi) << 16);
#endif
}
__device__ __forceinline__ float fexp2(float x) {
#if __has_builtin(__builtin_amdgcn_exp2f)
    return __builtin_amdgcn_exp2f(x);
#else
    return exp2f(x);
#endif
}

// ---------------------------------------------------------------------------
// fused prep: f32->bf16 for x/qkv_w/out_w, rope cos/sin table, bias wtab.
// Blocks [0, NBC): convert; [NBC, NBC+256): rope table; [NBC+256, +128): wtab.
// ---------------------------------------------------------------------------
#define NBC ((ROWS*DMODEL + NQKV*DMODEL + DMODEL*DMODEL) / 1024)
__global__ void prep_kernel(const float* __restrict__ a,
                            const float* __restrict__ b,
                            const float* __restrict__ c,
                            u16* __restrict__ oa, u16* __restrict__ ob,
                            u16* __restrict__ oc,
                            const float* __restrict__ freqs, float* __restrict__ cs_tab,
                            const float* __restrict__ bias_p,
                            const float* __restrict__ bias_a,
                            float* __restrict__ wtab)
{
    const int na = ROWS*DMODEL, nb = NQKV*DMODEL;
    int blk = blockIdx.x;
    if (blk < NBC) {
        int i = (blk * 256 + threadIdx.x) * 4;
        const float* s; u16* d; int base;
        if (i < na)           { s = a; d = oa; base = i; }
        else if (i < na + nb) { s = b; d = ob; base = i - na; }
        else                  { s = c; d = oc; base = i - na - nb; }
        float4 v = *(const float4*)(s + base);
        u16 o[4] = { f2bf(v.x), f2bf(v.y), f2bf(v.z), f2bf(v.w) };
        *(uint2*)(d + base) = *(const uint2*)o;
    } else if (blk < NBC + 256) {
        int idx = (blk - NBC) * 256 + threadIdx.x;   // SEQ*32
        int s = idx >> 5, d = idx & 31;
        float sn, cs;
        sincosf((float)s * freqs[d], &sn, &cs);
        cs_tab[idx * 2]     = cs;
        cs_tab[idx * 2 + 1] = sn;
    } else {
        int idx = (blk - NBC - 256) * 256 + threadIdx.x;  // NH*SEQ
        int h = idx >> 11;
        int d = idx & (SEQ - 1);
        float p = fmaxf(bias_p[h], 0.01f);
        float aa = fmaxf(bias_a[h], 0.01f);
        wtab[idx] = __expf(-p * log1pf(aa * (float)d));
    }
}

// ---------------------------------------------------------------------------
// QKV GEMM with fused RoPE + layout epilogue (verified R6/R7). 128x128 tile.
// ---------------------------------------------------------------------------
__global__ __launch_bounds__(256) void gemm_qkv(
    const u16* __restrict__ A, const u16* __restrict__ B,
    const float* __restrict__ cs_tab,
    u16* __restrict__ Qb, u16* __restrict__ Kb, u16* __restrict__ Vt)
{
    const int K = DMODEL;
    __shared__ __align__(16) u16 As[128][32];
    __shared__ __align__(16) u16 Bs[128][32];
    const int tid  = threadIdx.x;
    const int wave = tid >> 6, lane = tid & 63;
    const int quad = lane >> 4, l16 = lane & 15;
    const int wrow = (wave >> 1) * 64, wcol = (wave & 1) * 64;
    const int bm = blockIdx.x * 128, bn = blockIdx.y * 128;

    const int srow = lane >> 2;                       // 0..15
    const int scol = ((lane & 3) ^ (srow & 3)) * 8;   // swizzled chunk (u16)
    const int fsw = (quad ^ (l16 & 3)) * 8;           // frag read swizzle

    f32x4 acc[4][4];
#pragma unroll
    for (int i = 0; i < 4; ++i)
#pragma unroll
        for (int j = 0; j < 4; ++j) acc[i][j] = (f32x4){0.f,0.f,0.f,0.f};

    const u16* Ag0 = A + (size_t)(bm + wave*32 + srow)      * K + scol;
    const u16* Ag1 = A + (size_t)(bm + wave*32 + 16 + srow) * K + scol;
    const u16* Bg0 = B + (size_t)(bn + wave*32 + srow)      * K + scol;
    const u16* Bg1 = B + (size_t)(bn + wave*32 + 16 + srow) * K + scol;

    for (int k0 = 0; k0 < K; k0 += 32) {
        __syncthreads();
        gload16((lptr_t)&As[wave*32][0],      Ag0 + k0);
        gload16((lptr_t)&As[wave*32 + 16][0], Ag1 + k0);
        gload16((lptr_t)&Bs[wave*32][0],      Bg0 + k0);
        gload16((lptr_t)&Bs[wave*32 + 16][0], Bg1 + k0);
        __syncthreads();
        bf16x8 af[4], bfr[4];
#pragma unroll
        for (int i = 0; i < 4; ++i)
            af[i] = *(const bf16x8*)&As[wrow + i*16 + l16][fsw];
#pragma unroll
        for (int j = 0; j < 4; ++j)
            bfr[j] = *(const bf16x8*)&Bs[wcol + j*16 + l16][fsw];
#pragma unroll
        for (int i = 0; i < 4; ++i)
#pragma unroll
            for (int j = 0; j < 4; ++j)
                acc[i][j] = __builtin_amdgcn_mfma_f32_16x16x32_bf16(af[i], bfr[j], acc[i][j], 0, 0, 0);
    }

    // ---- fused epilogue ----
    const int tcol = (bn + wcol) >> 6;          // global 64-col index, 0..47
    const int t = tcol >> 4, h = tcol & 15;     // tensor (q/k/v), head
    const int bq = bm >> 11;                    // batch (tile never crosses)
    const int sb = (bm & (SEQ - 1)) + wrow;     // s base of this quadrant
    const size_t hb = (size_t)(bq * NH + h) * SEQ * HD;

    if (t == 2) {
#pragma unroll
        for (int i = 0; i < 4; ++i) {
            const int s = sb + i*16 + quad*4;
#pragma unroll
            for (int j = 0; j < 4; ++j) {
                const int d = j*16 + l16;
                uint2 pv = make_uint2(pk2(acc[i][j][0], acc[i][j][1]),
                                      pk2(acc[i][j][2], acc[i][j][3]));
                *(uint2*)&Vt[hb + (size_t)d * SEQ + s] = pv;
            }
        }
    } else {
        const float sc = (t == 0) ? QSCALE : 1.0f;
        u16* dstb = ((t == 0) ? Qb : Kb) + hb;
#pragma unroll
        for (int i = 0; i < 4; ++i) {
#pragma unroll
            for (int r = 0; r < 4; ++r) {
                const int s = sb + i*16 + quad*4 + r;
                const float2* ct = (const float2*)(cs_tab + ((size_t)s * 32 + l16) * 2);
                float2 cs0 = ct[0];     // freq idx l16
                float2 cs1 = ct[16];    // freq idx l16+16
                float a0 = acc[i][0][r], a1 = acc[i][1][r];
                float a2 = acc[i][2][r], a3 = acc[i][3][r];
                u16* dst = dstb + (size_t)s * HD;
                dst[l16]      = f2bf((a0*cs0.x - a2*cs0.y) * sc);
                dst[16 + l16] = f2bf((a1*cs1.x - a3*cs1.y) * sc);
                dst[32 + l16] = f2bf((a0*cs0.y + a2*cs0.x) * sc);
                dst[48 + l16] = f2bf((a1*cs1.y + a3*cs1.x) * sc);
            }
        }
    }
}

// ---------------------------------------------------------------------------
// out-projection GEMM: 128x64 tile (M x N) -> 512 blocks = 2+/CU for overlap.
// Wave w: rows (w>>1)*64, cols (w&1)*32. LDS 12 KB.
// ---------------------------------------------------------------------------
__global__ __launch_bounds__(256) void gemm_out(
    const u16* __restrict__ A, const u16* __restrict__ B,
    float* __restrict__ Cout, int M, int N, int K)
{
    __shared__ __align__(16) u16 As[128][32];
    __shared__ __align__(16) u16 Bs[64][32];
    const int tid  = threadIdx.x;
    const int wave = tid >> 6, lane = tid & 63;
    const int quad = lane >> 4, l16 = lane & 15;
    const int wrow = (wave >> 1) * 64, wcol = (wave & 1) * 32;
    const int bm = blockIdx.x * 128, bn = blockIdx.y * 64;

    const int srow = lane >> 2;
    const int scol = ((lane & 3) ^ (srow & 3)) * 8;
    const int fsw = (quad ^ (l16 & 3)) * 8;

    f32x4 acc[4][2];
#pragma unroll
    for (int i = 0; i < 4; ++i)
#pragma unroll
        for (int j = 0; j < 2; ++j) acc[i][j] = (f32x4){0.f,0.f,0.f,0.f};

    const u16* Ag0 = A + (size_t)(bm + wave*32 + srow)      * K + scol;
    const u16* Ag1 = A + (size_t)(bm + wave*32 + 16 + srow) * K + scol;
    const u16* Bg0 = B + (size_t)(bn + wave*16 + srow)      * K + scol;

    for (int k0 = 0; k0 < K; k0 += 32) {
        __syncthreads();
        gload16((lptr_t)&As[wave*32][0],      Ag0 + k0);
        gload16((lptr_t)&As[wave*32 + 16][0], Ag1 + k0);
        gload16((lptr_t)&Bs[wave*16][0],      Bg0 + k0);
        __syncthreads();
        bf16x8 af[4], bfr[2];
#pragma unroll
        for (int i = 0; i < 4; ++i)
            af[i] = *(const bf16x8*)&As[wrow + i*16 + l16][fsw];
#pragma unroll
        for (int j = 0; j < 2; ++j)
            bfr[j] = *(const bf16x8*)&Bs[wcol + j*16 + l16][fsw];
#pragma unroll
        for (int i = 0; i < 4; ++i)
#pragma unroll
            for (int j = 0; j < 2; ++j)
                acc[i][j] = __builtin_amdgcn_mfma_f32_16x16x32_bf16(af[i], bfr[j], acc[i][j], 0, 0, 0);
    }

#pragma unroll
    for (int i = 0; i < 4; ++i)
#pragma unroll
        for (int j = 0; j < 2; ++j) {
            int col = bn + wcol + j*16 + l16;
#pragma unroll
            for (int r = 0; r < 4; ++r) {
                int row = bm + wrow + i*16 + quad*4 + r;
                Cout[(size_t)row * N + col] = acc[i][j][r];
            }
        }
}

// ---------------------------------------------------------------------------
// MFMA flash attention v11: wave-private P, one barrier per tile.
// Wave w owns q rows q0+w*16..+15 and ALL 128 keys of each tile. Swapped QK
// (mfma(K,Q)) puts z for q=l16 in-lane; softmax in registers; PV contraction
// columns are PERMUTED (c=quad*8+j <-> key 16*(j>=4)+4*quad+(j&3)) applied to
// BOTH the P A-fragment and V B-fragment, so the P-frag is exactly the lane's
// own cvt_pk results - no cross-lane exchange, no P LDS, no P barriers.
//  - K fragments direct from global (all waves share lines -> L1).
//  - V DMA double-buffered; DMA issued after half-B K loads (sched_barrier
//    pins order so in-order vmcnt never forces the DMA drain early); drained
//    at the single end-of-tile barrier, covered by QKSM-B + PV.
//  - V B-frag: two swizzled ds_read_b64 (bank-minimal, verified).
//  LDS = 32K Vs + 1.5K ws2 + 0.25K linv ~= 34 KB -> 4 blocks/CU.
// ---------------------------------------------------------------------------
__global__ __launch_bounds__(256, 4) void attn_mfma(
    const u16* __restrict__ Qb, const u16* __restrict__ Kb,
    const u16* __restrict__ Vt, const float* __restrict__ wtab,
    u16* __restrict__ attn_bf)
{
    __shared__ __align__(16) u16 Vs[2][64*128]; // [buf][d][key], swizzled chunks
    __shared__ u32 ws2[2][192];                 // packed {w[m], w[m+1]}, dbuf
    __shared__ float linv[64];

    const int tid = threadIdx.x;
    const int wave = tid >> 6, lane = tid & 63;
    const int quad = lane >> 4, l16 = lane & 15;
    const int q0 = blockIdx.x * 64, h = blockIdx.y, b = blockIdx.z;

    const u16* Qh = Qb + (size_t)(b * NH + h) * SEQ * HD;
    const u16* Kh = Kb + (size_t)(b * NH + h) * SEQ * HD;
    const u16* Vh = Vt + (size_t)(b * NH + h) * HD * SEQ;
    const float* wh = wtab + h * SEQ;

    // Q fragments: this wave's 16 q rows (q = q0 + wave*16 + l16)
    const u16* qr = Qh + (size_t)(q0 + wave*16 + l16) * HD + quad * 8;
    const bf16x8 qf0 = *(const bf16x8*)qr;
    const bf16x8 qf1 = *(const bf16x8*)(qr + 32);

    // K fragment base: group g of tile kt -> key row kt*128 + g*16 + l16
    const u16* Kf = Kh + (size_t)l16 * HD + quad * 8;

    // V staging (DMA): rows wave*16 + i*4 + (lane>>4), chunk' = chunk^(d&7)
    const int vsrow = lane >> 4;
    const u16* Vst[4];
#pragma unroll
    for (int i = 0; i < 4; ++i) {
        int d = wave*16 + i*4 + vsrow;
        int vscol = ((lane & 15) ^ (d & 7)) * 8;
        Vst[i] = Vh + (size_t)d * SEQ + vscol;
    }

    // bias window base: w index for (g, r) is (mb0 - 16g) + 3 - r
    const int mb0 = 127 + wave*16 + l16 - quad*4 - 3;

    float l_p = 0.f;
    f32x4 o[4];
#pragma unroll
    for (int j = 0; j < 4; ++j) o[j] = (f32x4){0.f,0.f,0.f,0.f};

    // ---- prologue: DMA tile 0 -> Vs[0]; bias window 0 -> ws2[0] ----
#pragma unroll
    for (int i = 0; i < 4; ++i)
        gload16((lptr_t)&Vs[0][(wave*16 + i*4)*128], Vst[i]);
    if (tid < 192) {
        int i0 = (q0 - 127) + tid;
        int a0 = i0 < 0 ? -i0 : i0;  if (a0 > SEQ-1) a0 = SEQ-1;
        int i1 = i0 + 1;
        int a1 = i1 < 0 ? -i1 : i1;  if (a1 > SEQ-1) a1 = SEQ-1;
        ws2[0][tid] = pk2(wh[a0], wh[a1]);
    }
    __syncthreads();

    for (int kt = 0; kt < NT; ++kt) {
        const int cur = kt & 1;
        const u32* wsb = ws2[cur];
        const u16* Kt = Kf + (size_t)(kt * 128) * HD;
        u32 y[16];
        bf16x8 ka[8];

        // ---- half A: K loads for groups 0..3, then QK+softmax ----
#pragma unroll
        for (int g = 0; g < 4; ++g) {
            const u16* kp = Kt + (size_t)(g * 16) * HD;
            ka[2*g]   = *(const bf16x8*)kp;
            ka[2*g+1] = *(const bf16x8*)(kp + 32);
        }
#pragma unroll
        for (int g = 0; g < 4; ++g) {
            f32x4 z = (f32x4){0.f,0.f,0.f,0.f};
            z = __builtin_amdgcn_mfma_f32_16x16x32_bf16(ka[2*g],   qf0, z, 0, 0, 0);
            z = __builtin_amdgcn_mfma_f32_16x16x32_bf16(ka[2*g+1], qf1, z, 0, 0, 0);
            const int mbase = mb0 - 16*g;
            u32 pA = wsb[mbase], pB = wsb[mbase + 2];
            float w3 = __uint_as_float(pA << 16);
            float w2 = __uint_as_float(pA & 0xffff0000u);
            float w1 = __uint_as_float(pB << 16);
            float w0 = __uint_as_float(pB & 0xffff0000u);
            float e0 = fexp2(z[0]) * w0, e1 = fexp2(z[1]) * w1;
            float e2 = fexp2(z[2]) * w2, e3 = fexp2(z[3]) * w3;
            l_p += (e0 + e1) + (e2 + e3);
            y[2*g]   = pk2(e0, e1);
            y[2*g+1] = pk2(e2, e3);
        }

        // ---- half B: K loads for groups 4..7 (BEFORE the DMA: in-order
        //      vmcnt means any load issued after the DMA would force its
        //      drain when awaited) ----
#pragma unroll
        for (int g = 0; g < 4; ++g) {
            const u16* kp = Kt + (size_t)((g + 4) * 16) * HD;
            ka[2*g]   = *(const bf16x8*)kp;
            ka[2*g+1] = *(const bf16x8*)(kp + 32);
        }
        __builtin_amdgcn_sched_barrier(0);  // pin: kfB loads stay above DMA

        // ---- issue next tile's V DMA; drains at end-of-tile barrier,
        //      covered by QKSM-B + PV ----
        if (kt + 1 < NT) {
#pragma unroll
            for (int i = 0; i < 4; ++i)
                gload16((lptr_t)&Vs[cur ^ 1][(wave*16 + i*4)*128],
                        Vst[i] + (kt + 1) * 128);
        }

#pragma unroll
        for (int g = 0; g < 4; ++g) {
            f32x4 z = (f32x4){0.f,0.f,0.f,0.f};
            z = __builtin_amdgcn_mfma_f32_16x16x32_bf16(ka[2*g],   qf0, z, 0, 0, 0);
            z = __builtin_amdgcn_mfma_f32_16x16x32_bf16(ka[2*g+1], qf1, z, 0, 0, 0);
            const int mbase = mb0 - 16*(g + 4);
            u32 pA = wsb[mbase], pB = wsb[mbase + 2];
            float w3 = __uint_as_float(pA << 16);
            float w2 = __uint_as_float(pA & 0xffff0000u);
            float w1 = __uint_as_float(pB << 16);
            float w0 = __uint_as_float(pB & 0xffff0000u);
            float e0 = fexp2(z[0]) * w0, e1 = fexp2(z[1]) * w1;
            float e2 = fexp2(z[2]) * w2, e3 = fexp2(z[3]) * w3;
            l_p += (e0 + e1) + (e2 + e3);
            y[8 + 2*g] = pk2(e0, e1);
            y[9 + 2*g] = pk2(e2, e3);
        }

        // ---- PV: o[j] += P(permuted cols) * V, V from Vs[cur] ----
#pragma unroll
        for (int s = 0; s < 4; ++s) {
            union { u32 u[4]; bf16x8 v; } pfu;
            pfu.u[0] = y[4*s];     pfu.u[1] = y[4*s + 1];
            pfu.u[2] = y[4*s + 2]; pfu.u[3] = y[4*s + 3];
#pragma unroll
            for (int j = 0; j < 4; ++j) {
                const int d = j*16 + l16;
                const int rb = d*128 + (quad & 1)*4;
                const int c0 = (4*s     + (quad >> 1)) ^ (l16 & 7);
                const int c1 = (4*s + 2 + (quad >> 1)) ^ (l16 & 7);
                uint2 va = *(const uint2*)&Vs[cur][rb + c0*8];
                uint2 vb = *(const uint2*)&Vs[cur][rb + c1*8];
                union { uint4 u; bf16x8 v; } vfu;
                vfu.u = make_uint4(va.x, va.y, vb.x, vb.y);
                o[j] = __builtin_amdgcn_mfma_f32_16x16x32_bf16(pfu.v, vfu.v, o[j], 0, 0, 0);
            }
        }

        // ---- stage next tile's bias window (end of tile; DMA drains at
        //      the barrier anyway) ----
        if (kt + 1 < NT && tid < 192) {
            int i0 = (q0 - (kt + 1)*128 - 127) + tid;
            int a0 = i0 < 0 ? -i0 : i0;  if (a0 > SEQ-1) a0 = SEQ-1;
            int i1 = i0 + 1;
            int a1 = i1 < 0 ? -i1 : i1;  if (a1 > SEQ-1) a1 = SEQ-1;
            ws2[cur ^ 1][tid] = pk2(wh[a0], wh[a1]);
        }
        __syncthreads();   // one barrier/tile: V(t+1) drained; Vs[cur] reads done
    }

    // ---- epilogue: l across quads (in-lane q=l16), then store ----
    l_p += __shfl_xor(l_p, 16);
    l_p += __shfl_xor(l_p, 32);
    if (quad == 0) linv[wave*16 + l16] = 1.0f / l_p;
    __syncthreads();
#pragma unroll
    for (int r = 0; r < 4; ++r) {
        const int q = wave*16 + quad*4 + r;
        float inv = linv[q];
        u16* dst = attn_bf + (size_t)(b * SEQ + q0 + q) * DMODEL + h * HD;
#pragma unroll
        for (int j = 0; j < 4; ++j)
            dst[j*16 + l16] = f2bf(o[j][r] * inv);
    }
}

// ---------------------------------------------------------------------------
extern "C" void kernel_launch(void* const* d_in, const int* in_sizes, int n_in,
                              void* d_out, int out_size, void* d_ws, size_t ws_size,
                              hipStream_t stream)
{
    (void)in_sizes; (void)n_in; (void)out_size; (void)ws_size;
    const float* x      = (const float*)d_in[0];
    const float* qkv_w  = (const float*)d_in[1];
    const float* out_w  = (const float*)d_in[2];
    const float* bias_p = (const float*)d_in[3];
    const float* bias_a = (const float*)d_in[4];
    const float* freqs  = (const float*)d_in[5];
    float* out = (float*)d_out;

    // ws layout (bytes):
    //   [0, 8M)       attn_bf [4096][1024] bf16
    //   [8M, 16M)     Qb      [2][16][2048][64] bf16
    //   [24M, 32M)    x_bf    [4096][1024] bf16
    //   [32M, 38M)    w1_bf   [3072][1024] bf16
    //   [38M, 40M)    w2_bf   [1024][1024] bf16
    //   [40M, 48M)    Kb      [2][16][2048][64] bf16
    //   [48M, 56M)    Vt      [2][16][64][2048] bf16
    //   [56M, +128K)  wtab    [16][2048] f32 (exp of bias)
    //   [+128K,+640K) cs_tab  [2048][32][2] f32
    char* ws = (char*)d_ws;
    u16*   attn_bf = (u16*)ws;
    u16*   Qb      = (u16*)(ws + 8388608);
    u16*   x_bf    = (u16*)(ws + 25165824);
    u16*   w1_bf   = (u16*)(ws + 33554432);
    u16*   w2_bf   = (u16*)(ws + 39845888);
    u16*   Kb      = (u16*)(ws + 41943040);
    u16*   Vt      = (u16*)(ws + 50331648);
    float* wtab    = (float*)(ws + 58720256);
    float* cs_tab  = (float*)(ws + 58720256 + 131072);

    prep_kernel<<<dim3(NBC + 256 + 128), 256, 0, stream>>>(
        x, qkv_w, out_w, x_bf, w1_bf, w2_bf, freqs, cs_tab, bias_p, bias_a, wtab);

    gemm_qkv<<<dim3(ROWS/128, NQKV/128), 256, 0, stream>>>(x_bf, w1_bf, cs_tab, Qb, Kb, Vt);
    attn_mfma<<<dim3(SEQ/64, NH, BATCH), 256, 0, stream>>>(Qb, Kb, Vt, wtab, attn_bf);
    gemm_out<<<dim3(ROWS/128, DMODEL/64), 256, 0, stream>>>(attn_bf, w2_bf, out, ROWS, DMODEL, DMODEL);
}

// Round 7
// 250.991 us; speedup vs baseline: 1.1376x; 1.1376x over previous
//
#include <hip/hip_runtime.h>
#include <math.h>

#define BATCH  2
#define SEQ    2048
#define DMODEL 1024
#define NH     16
#define HD     64
#define NQKV   3072
#define ROWS   (BATCH*SEQ)
#define NT     (SEQ/128)
#define QSCALE 0.18033688f   // 0.125 * log2(e): QK^T scores land in log2 domain

typedef unsigned short u16;
typedef unsigned int   u32;
typedef __bf16 bf16x8 __attribute__((ext_vector_type(8)));
typedef float  f32x4  __attribute__((ext_vector_type(4)));

typedef const __attribute__((address_space(1))) void* gptr_t;
typedef __attribute__((address_space(3))) void* lptr_t;

__device__ __forceinline__ void gload16(lptr_t l, const void* g) {
    __builtin_amdgcn_global_load_lds((gptr_t)g, l, 16, 0, 0);
}

__device__ __forceinline__ u16 f2bf(float f) {          // RNE f32->bf16
    unsigned int u = __float_as_uint(f);
    u += 0x7FFFu + ((u >> 16) & 1u);
    return (u16)(u >> 16);
}
__device__ __forceinline__ u32 pk2(float lo, float hi) { // pack 2 f32 -> 2 bf16
#if __has_builtin(__builtin_amdgcn_cvt_pk_bf16_f32)
    typedef __bf16 bf16x2 __attribute__((ext_vector_type(2)));
    union { bf16x2 v; u32 u; } cv;
    cv.v = __builtin_amdgcn_cvt_pk_bf16_f32(lo, hi);
    return cv.u;
#else
    return (u32)f2bf(lo) | ((u32)f2bf(hi) << 16);
#endif
}
__device__ __forceinline__ float fexp2(float x) {
#if __has_builtin(__builtin_amdgcn_exp2f)
    return __builtin_amdgcn_exp2f(x);
#else
    return exp2f(x);
#endif
}

// ---------------------------------------------------------------------------
// fused prep: f32->bf16 for x/qkv_w/out_w, rope cos/sin table, bias wtab.
// Blocks [0, NBC): convert; [NBC, NBC+256): rope table; [NBC+256, +128): wtab.
// ---------------------------------------------------------------------------
#define NBC ((ROWS*DMODEL + NQKV*DMODEL + DMODEL*DMODEL) / 1024)
__global__ void prep_kernel(const float* __restrict__ a,
                            const float* __restrict__ b,
                            const float* __restrict__ c,
                            u16* __restrict__ oa, u16* __restrict__ ob,
                            u16* __restrict__ oc,
                            const float* __restrict__ freqs, float* __restrict__ cs_tab,
                            const float* __restrict__ bias_p,
                            const float* __restrict__ bias_a,
                            float* __restrict__ wtab)
{
    const int na = ROWS*DMODEL, nb = NQKV*DMODEL;
    int blk = blockIdx.x;
    if (blk < NBC) {
        int i = (blk * 256 + threadIdx.x) * 4;
        const float* s; u16* d; int base;
        if (i < na)           { s = a; d = oa; base = i; }
        else if (i < na + nb) { s = b; d = ob; base = i - na; }
        else                  { s = c; d = oc; base = i - na - nb; }
        float4 v = *(const float4*)(s + base);
        u16 o[4] = { f2bf(v.x), f2bf(v.y), f2bf(v.z), f2bf(v.w) };
        *(uint2*)(d + base) = *(const uint2*)o;
    } else if (blk < NBC + 256) {
        int idx = (blk - NBC) * 256 + threadIdx.x;   // SEQ*32
        int s = idx >> 5, d = idx & 31;
        float sn, cs;
        sincosf((float)s * freqs[d], &sn, &cs);
        cs_tab[idx * 2]     = cs;
        cs_tab[idx * 2 + 1] = sn;
    } else {
        int idx = (blk - NBC - 256) * 256 + threadIdx.x;  // NH*SEQ
        int h = idx >> 11;
        int d = idx & (SEQ - 1);
        float p = fmaxf(bias_p[h], 0.01f);
        float aa = fmaxf(bias_a[h], 0.01f);
        wtab[idx] = __expf(-p * log1pf(aa * (float)d));
    }
}

// ---------------------------------------------------------------------------
// QKV GEMM with fused RoPE + layout epilogue (verified R6/R7). 128x128 tile.
// ---------------------------------------------------------------------------
__global__ __launch_bounds__(256) void gemm_qkv(
    const u16* __restrict__ A, const u16* __restrict__ B,
    const float* __restrict__ cs_tab,
    u16* __restrict__ Qb, u16* __restrict__ Kb, u16* __restrict__ Vt)
{
    const int K = DMODEL;
    __shared__ __align__(16) u16 As[128][32];
    __shared__ __align__(16) u16 Bs[128][32];
    const int tid  = threadIdx.x;
    const int wave = tid >> 6, lane = tid & 63;
    const int quad = lane >> 4, l16 = lane & 15;
    const int wrow = (wave >> 1) * 64, wcol = (wave & 1) * 64;
    const int bm = blockIdx.x * 128, bn = blockIdx.y * 128;

    const int srow = lane >> 2;                       // 0..15
    const int scol = ((lane & 3) ^ (srow & 3)) * 8;   // swizzled chunk (u16)
    const int fsw = (quad ^ (l16 & 3)) * 8;           // frag read swizzle

    f32x4 acc[4][4];
#pragma unroll
    for (int i = 0; i < 4; ++i)
#pragma unroll
        for (int j = 0; j < 4; ++j) acc[i][j] = (f32x4){0.f,0.f,0.f,0.f};

    const u16* Ag0 = A + (size_t)(bm + wave*32 + srow)      * K + scol;
    const u16* Ag1 = A + (size_t)(bm + wave*32 + 16 + srow) * K + scol;
    const u16* Bg0 = B + (size_t)(bn + wave*32 + srow)      * K + scol;
    const u16* Bg1 = B + (size_t)(bn + wave*32 + 16 + srow) * K + scol;

    for (int k0 = 0; k0 < K; k0 += 32) {
        __syncthreads();
        gload16((lptr_t)&As[wave*32][0],      Ag0 + k0);
        gload16((lptr_t)&As[wave*32 + 16][0], Ag1 + k0);
        gload16((lptr_t)&Bs[wave*32][0],      Bg0 + k0);
        gload16((lptr_t)&Bs[wave*32 + 16][0], Bg1 + k0);
        __syncthreads();
        bf16x8 af[4], bfr[4];
#pragma unroll
        for (int i = 0; i < 4; ++i)
            af[i] = *(const bf16x8*)&As[wrow + i*16 + l16][fsw];
#pragma unroll
        for (int j = 0; j < 4; ++j)
            bfr[j] = *(const bf16x8*)&Bs[wcol + j*16 + l16][fsw];
#pragma unroll
        for (int i = 0; i < 4; ++i)
#pragma unroll
            for (int j = 0; j < 4; ++j)
                acc[i][j] = __builtin_amdgcn_mfma_f32_16x16x32_bf16(af[i], bfr[j], acc[i][j], 0, 0, 0);
    }

    // ---- fused epilogue ----
    const int tcol = (bn + wcol) >> 6;          // global 64-col index, 0..47
    const int t = tcol >> 4, h = tcol & 15;     // tensor (q/k/v), head
    const int bq = bm >> 11;                    // batch (tile never crosses)
    const int sb = (bm & (SEQ - 1)) + wrow;     // s base of this quadrant
    const size_t hb = (size_t)(bq * NH + h) * SEQ * HD;

    if (t == 2) {
#pragma unroll
        for (int i = 0; i < 4; ++i) {
            const int s = sb + i*16 + quad*4;
#pragma unroll
            for (int j = 0; j < 4; ++j) {
                const int d = j*16 + l16;
                uint2 pv = make_uint2(pk2(acc[i][j][0], acc[i][j][1]),
                                      pk2(acc[i][j][2], acc[i][j][3]));
                *(uint2*)&Vt[hb + (size_t)d * SEQ + s] = pv;
            }
        }
    } else {
        const float sc = (t == 0) ? QSCALE : 1.0f;
        u16* dstb = ((t == 0) ? Qb : Kb) + hb;
#pragma unroll
        for (int i = 0; i < 4; ++i) {
#pragma unroll
            for (int r = 0; r < 4; ++r) {
                const int s = sb + i*16 + quad*4 + r;
                const float2* ct = (const float2*)(cs_tab + ((size_t)s * 32 + l16) * 2);
                float2 cs0 = ct[0];     // freq idx l16
                float2 cs1 = ct[16];    // freq idx l16+16
                float a0 = acc[i][0][r], a1 = acc[i][1][r];
                float a2 = acc[i][2][r], a3 = acc[i][3][r];
                u16* dst = dstb + (size_t)s * HD;
                dst[l16]      = f2bf((a0*cs0.x - a2*cs0.y) * sc);
                dst[16 + l16] = f2bf((a1*cs1.x - a3*cs1.y) * sc);
                dst[32 + l16] = f2bf((a0*cs0.y + a2*cs0.x) * sc);
                dst[48 + l16] = f2bf((a1*cs1.y + a3*cs1.x) * sc);
            }
        }
    }
}

// ---------------------------------------------------------------------------
// out-projection GEMM: 128x64 tile (M x N) -> 512 blocks = 2+/CU for overlap.
// Wave w: rows (w>>1)*64, cols (w&1)*32. LDS 12 KB.
// ---------------------------------------------------------------------------
__global__ __launch_bounds__(256) void gemm_out(
    const u16* __restrict__ A, const u16* __restrict__ B,
    float* __restrict__ Cout, int M, int N, int K)
{
    __shared__ __align__(16) u16 As[128][32];
    __shared__ __align__(16) u16 Bs[64][32];
    const int tid  = threadIdx.x;
    const int wave = tid >> 6, lane = tid & 63;
    const int quad = lane >> 4, l16 = lane & 15;
    const int wrow = (wave >> 1) * 64, wcol = (wave & 1) * 32;
    const int bm = blockIdx.x * 128, bn = blockIdx.y * 64;

    const int srow = lane >> 2;
    const int scol = ((lane & 3) ^ (srow & 3)) * 8;
    const int fsw = (quad ^ (l16 & 3)) * 8;

    f32x4 acc[4][2];
#pragma unroll
    for (int i = 0; i < 4; ++i)
#pragma unroll
        for (int j = 0; j < 2; ++j) acc[i][j] = (f32x4){0.f,0.f,0.f,0.f};

    const u16* Ag0 = A + (size_t)(bm + wave*32 + srow)      * K + scol;
    const u16* Ag1 = A + (size_t)(bm + wave*32 + 16 + srow) * K + scol;
    const u16* Bg0 = B + (size_t)(bn + wave*16 + srow)      * K + scol;

    for (int k0 = 0; k0 < K; k0 += 32) {
        __syncthreads();
        gload16((lptr_t)&As[wave*32][0],      Ag0 + k0);
        gload16((lptr_t)&As[wave*32 + 16][0], Ag1 + k0);
        gload16((lptr_t)&Bs[wave*16][0],      Bg0 + k0);
        __syncthreads();
        bf16x8 af[4], bfr[2];
#pragma unroll
        for (int i = 0; i < 4; ++i)
            af[i] = *(const bf16x8*)&As[wrow + i*16 + l16][fsw];
#pragma unroll
        for (int j = 0; j < 2; ++j)
            bfr[j] = *(const bf16x8*)&Bs[wcol + j*16 + l16][fsw];
#pragma unroll
        for (int i = 0; i < 4; ++i)
#pragma unroll
            for (int j = 0; j < 2; ++j)
                acc[i][j] = __builtin_amdgcn_mfma_f32_16x16x32_bf16(af[i], bfr[j], acc[i][j], 0, 0, 0);
    }

#pragma unroll
    for (int i = 0; i < 4; ++i)
#pragma unroll
        for (int j = 0; j < 2; ++j) {
            int col = bn + wcol + j*16 + l16;
#pragma unroll
            for (int r = 0; r < 4; ++r) {
                int row = bm + wrow + i*16 + quad*4 + r;
                Cout[(size_t)row * N + col] = acc[i][j][r];
            }
        }
}

// ---------------------------------------------------------------------------
// MFMA flash attention v12: wave = (q-half, key-half); P never leaves the
// wave; ONE barrier per tile.
// Wave w: qh=w>>1 owns q rows qh*32..+32; kh=w&1 owns keys kh*64..+64 of the
// 128-key tile. QK per wave: 4 groups x 2 qj = 16 MFMA (z col=q=l16,
// row=key quad*4+r). Softmax in-register -> y packs. PV contracts ONLY the
// wave's own keys with the contract-slot permutation
//   slot quad*8 + kg*4 + r  <->  key kg*16 + quad*4 + r   (bijective)
// applied to BOTH operands: A-frag = the lane's own y values (no exchange!),
// B-frag = two ds_read_b64 per (dj,half) through the existing chunk swizzle
// (bank-checked: ((c^(l16&7))%8)*4+(quad&1)*2 spreads all banks).
// Partial O (32q x 64d, 32 VGPR) accumulates across tiles; one LDS merge of
// the two key-halves at kernel end (scratch aliases the dead Vs).
// kf loads issued BEFORE the V-DMA so in-order vmcnt never drains the DMA;
// the DMA is covered by the whole tile body. 1 barrier/tile.
// LDS = 32K Vs + 1.5K ws2 + 0.75K misc ~= 35 KB.
// ---------------------------------------------------------------------------
__global__ __launch_bounds__(256, 3) void attn_mfma(
    const u16* __restrict__ Qb, const u16* __restrict__ Kb,
    const u16* __restrict__ Vt, const float* __restrict__ wtab,
    u16* __restrict__ attn_bf)
{
    __shared__ __align__(16) u16 Vs[2][64*128]; // [buf][d][key], chunk-swizzled
    __shared__ u32 ws2[2][192];                 // packed {w[m], w[m+1]}, dbuf
    __shared__ float lred[4][32];
    __shared__ float linv[64];

    const int tid = threadIdx.x;
    const int wave = tid >> 6, lane = tid & 63;
    const int quad = lane >> 4, l16 = lane & 15;
    const int qh = wave >> 1, kh = wave & 1;
    const int q0 = blockIdx.x * 64, h = blockIdx.y, b = blockIdx.z;

    const u16* Qh = Qb + (size_t)(b * NH + h) * SEQ * HD;
    const u16* Kh = Kb + (size_t)(b * NH + h) * SEQ * HD;
    const u16* Vh = Vt + (size_t)(b * NH + h) * HD * SEQ;
    const float* wh = wtab + h * SEQ;

    // Q fragments: rows q0 + qh*32 + qj*16 + l16 (qj = 0,1)
    bf16x8 qf0[2], qf1[2];
#pragma unroll
    for (int qj = 0; qj < 2; ++qj) {
        const u16* qr = Qh + (size_t)(q0 + qh*32 + qj*16 + l16) * HD + quad * 8;
        qf0[qj] = *(const bf16x8*)qr;
        qf1[qj] = *(const bf16x8*)(qr + 32);
    }

    // K fragment base: key = kt*128 + kh*64 + g*16 + l16
    const u16* Kf = Kh + (size_t)(kh*64 + l16) * HD + quad * 8;

    // V staging (DMA): rows wave*16 + i*4 + (lane>>4); chunk' = chunk^(d&7)
    const int vsrow = lane >> 4;
    const u16* Vst[4];
#pragma unroll
    for (int i = 0; i < 4; ++i) {
        int d = wave*16 + i*4 + vsrow;
        int vscol = ((lane & 15) ^ (d & 7)) * 8;
        Vst[i] = Vh + (size_t)d * SEQ + vscol;
    }

    // bias-window base: t(g,qj,r) = mb0 + qj*16 - g*16 + (3 - r)
    const int mb0 = 127 + qh*32 + l16 - kh*64 - quad*4 - 3;

    float l_p[2] = {0.f, 0.f};
    f32x4 o[2][4];
#pragma unroll
    for (int qj = 0; qj < 2; ++qj)
#pragma unroll
        for (int dj = 0; dj < 4; ++dj) o[qj][dj] = (f32x4){0.f,0.f,0.f,0.f};

    // ---- prologue: DMA tile 0 -> Vs[0]; bias window 0 -> ws2[0] ----
#pragma unroll
    for (int i = 0; i < 4; ++i)
        gload16((lptr_t)&Vs[0][(wave*16 + i*4)*128], Vst[i]);
    if (tid < 192) {
        int i0 = (q0 - 127) + tid;
        int a0 = i0 < 0 ? -i0 : i0;  if (a0 > SEQ-1) a0 = SEQ-1;
        int i1 = i0 + 1;
        int a1 = i1 < 0 ? -i1 : i1;  if (a1 > SEQ-1) a1 = SEQ-1;
        ws2[0][tid] = pk2(wh[a0], wh[a1]);
    }
    __syncthreads();

    for (int kt = 0; kt < NT; ++kt) {
        const int cur = kt & 1;
        const u32* wsb = ws2[cur];
        const u16* Kt = Kf + (size_t)(kt * 128) * HD;

        // ---- all 8 kf loads FIRST (so kf waits never drain the DMA) ----
        bf16x8 kf[4][2];
#pragma unroll
        for (int g = 0; g < 4; ++g) {
            const u16* kp = Kt + (size_t)(g * 16) * HD;
            kf[g][0] = *(const bf16x8*)kp;
            kf[g][1] = *(const bf16x8*)(kp + 32);
        }
        __builtin_amdgcn_sched_barrier(0);

        // ---- issue next tile's V DMA; drains at end-of-tile barrier ----
        if (kt + 1 < NT) {
#pragma unroll
            for (int i = 0; i < 4; ++i)
                gload16((lptr_t)&Vs[cur ^ 1][(wave*16 + i*4)*128],
                        Vst[i] + (kt + 1) * 128);
        }

        // ---- QK + softmax -> y (all in registers) ----
        u32 y[2][8];
#pragma unroll
        for (int g = 0; g < 4; ++g) {
#pragma unroll
            for (int qj = 0; qj < 2; ++qj) {
                f32x4 z = (f32x4){0.f,0.f,0.f,0.f};
                z = __builtin_amdgcn_mfma_f32_16x16x32_bf16(kf[g][0], qf0[qj], z, 0, 0, 0);
                z = __builtin_amdgcn_mfma_f32_16x16x32_bf16(kf[g][1], qf1[qj], z, 0, 0, 0);
                const int mbase = mb0 + qj*16 - g*16;
                u32 pA = wsb[mbase], pB = wsb[mbase + 2];
                float w3 = __uint_as_float(pA << 16);
                float w2 = __uint_as_float(pA & 0xffff0000u);
                float w1 = __uint_as_float(pB << 16);
                float w0 = __uint_as_float(pB & 0xffff0000u);
                float e0 = fexp2(z[0]) * w0, e1 = fexp2(z[1]) * w1;
                float e2 = fexp2(z[2]) * w2, e3 = fexp2(z[3]) * w3;
                l_p[qj] += (e0 + e1) + (e2 + e3);
                y[qj][g*2]     = pk2(e0, e1);
                y[qj][g*2 + 1] = pk2(e2, e3);
            }
        }

        // ---- PV: o[qj][dj] += P(own keys, permuted slots) * V ----
#pragma unroll
        for (int dj = 0; dj < 4; ++dj) {
            const int drow = (dj*16 + l16) * 128;
            const int cbase = kh*8 + (quad >> 1);
            const int coff  = (quad & 1) * 4;
            uint2 v00 = *(const uint2*)&Vs[cur][drow + (((cbase    ) ^ (l16 & 7)) * 8) + coff];
            uint2 v01 = *(const uint2*)&Vs[cur][drow + (((cbase + 2) ^ (l16 & 7)) * 8) + coff];
            uint2 v10 = *(const uint2*)&Vs[cur][drow + (((cbase + 4) ^ (l16 & 7)) * 8) + coff];
            uint2 v11 = *(const uint2*)&Vs[cur][drow + (((cbase + 6) ^ (l16 & 7)) * 8) + coff];
            union { uint4 u; bf16x8 v; } vf0, vf1;
            vf0.u = make_uint4(v00.x, v00.y, v01.x, v01.y);   // half 0: kg0,kg1
            vf1.u = make_uint4(v10.x, v10.y, v11.x, v11.y);   // half 1: kg0,kg1
#pragma unroll
            for (int qj = 0; qj < 2; ++qj) {
                union { u32 u[4]; bf16x8 v; } pf0, pf1;
                pf0.u[0] = y[qj][0]; pf0.u[1] = y[qj][1];
                pf0.u[2] = y[qj][2]; pf0.u[3] = y[qj][3];
                pf1.u[0] = y[qj][4]; pf1.u[1] = y[qj][5];
                pf1.u[2] = y[qj][6]; pf1.u[3] = y[qj][7];
                o[qj][dj] = __builtin_amdgcn_mfma_f32_16x16x32_bf16(pf0.v, vf0.v, o[qj][dj], 0, 0, 0);
                o[qj][dj] = __builtin_amdgcn_mfma_f32_16x16x32_bf16(pf1.v, vf1.v, o[qj][dj], 0, 0, 0);
            }
        }

        // ---- stage next tile's bias window ----
        if (kt + 1 < NT && tid < 192) {
            int i0 = (q0 - (kt + 1)*128 - 127) + tid;
            int a0 = i0 < 0 ? -i0 : i0;  if (a0 > SEQ-1) a0 = SEQ-1;
            int i1 = i0 + 1;
            int a1 = i1 < 0 ? -i1 : i1;  if (a1 > SEQ-1) a1 = SEQ-1;
            ws2[cur ^ 1][tid] = pk2(wh[a0], wh[a1]);
        }
        __syncthreads();   // one barrier/tile: DMA drained; Vs[cur]/ws2 reads done
    }

    // ---- epilogue: merge key-halves via LDS (aliases dead Vs), store ----
#pragma unroll
    for (int qj = 0; qj < 2; ++qj) {
        float l = l_p[qj];
        l += __shfl_xor(l, 16);
        l += __shfl_xor(l, 32);
        if (quad == 0) lred[wave][qj*16 + l16] = l;
    }
    float* sc = (float*)&Vs[0][0];          // [64 q][68] f32 scratch (17 KB)
    if (kh == 0) {
#pragma unroll
        for (int qj = 0; qj < 2; ++qj)
#pragma unroll
            for (int dj = 0; dj < 4; ++dj)
#pragma unroll
                for (int r = 0; r < 4; ++r)
                    sc[(qh*32 + qj*16 + quad*4 + r)*68 + dj*16 + l16] = o[qj][dj][r];
    }
    __syncthreads();
    if (tid < 64)
        linv[tid] = 1.0f / (lred[(tid >> 5)*2][tid & 31] + lred[(tid >> 5)*2 + 1][tid & 31]);
    __syncthreads();
    if (kh == 1) {
#pragma unroll
        for (int qj = 0; qj < 2; ++qj)
#pragma unroll
            for (int r = 0; r < 4; ++r) {
                const int q = qh*32 + qj*16 + quad*4 + r;
                float inv = linv[q];
                u16* dst = attn_bf + (size_t)(b * SEQ + q0 + q) * DMODEL + h * HD;
#pragma unroll
                for (int dj = 0; dj < 4; ++dj)
                    dst[dj*16 + l16] =
                        f2bf((o[qj][dj][r] + sc[q*68 + dj*16 + l16]) * inv);
            }
    }
}

// ---------------------------------------------------------------------------
extern "C" void kernel_launch(void* const* d_in, const int* in_sizes, int n_in,
                              void* d_out, int out_size, void* d_ws, size_t ws_size,
                              hipStream_t stream)
{
    (void)in_sizes; (void)n_in; (void)out_size; (void)ws_size;
    const float* x      = (const float*)d_in[0];
    const float* qkv_w  = (const float*)d_in[1];
    const float* out_w  = (const float*)d_in[2];
    const float* bias_p = (const float*)d_in[3];
    const float* bias_a = (const float*)d_in[4];
    const float* freqs  = (const float*)d_in[5];
    float* out = (float*)d_out;

    // ws layout (bytes):
    //   [0, 8M)       attn_bf [4096][1024] bf16
    //   [8M, 16M)     Qb      [2][16][2048][64] bf16
    //   [24M, 32M)    x_bf    [4096][1024] bf16
    //   [32M, 38M)    w1_bf   [3072][1024] bf16
    //   [38M, 40M)    w2_bf   [1024][1024] bf16
    //   [40M, 48M)    Kb      [2][16][2048][64] bf16
    //   [48M, 56M)    Vt      [2][16][64][2048] bf16
    //   [56M, +128K)  wtab    [16][2048] f32 (exp of bias)
    //   [+128K,+640K) cs_tab  [2048][32][2] f32
    char* ws = (char*)d_ws;
    u16*   attn_bf = (u16*)ws;
    u16*   Qb      = (u16*)(ws + 8388608);
    u16*   x_bf    = (u16*)(ws + 25165824);
    u16*   w1_bf   = (u16*)(ws + 33554432);
    u16*   w2_bf   = (u16*)(ws + 39845888);
    u16*   Kb      = (u16*)(ws + 41943040);
    u16*   Vt      = (u16*)(ws + 50331648);
    float* wtab    = (float*)(ws + 58720256);
    float* cs_tab  = (float*)(ws + 58720256 + 131072);

    prep_kernel<<<dim3(NBC + 256 + 128), 256, 0, stream>>>(
        x, qkv_w, out_w, x_bf, w1_bf, w2_bf, freqs, cs_tab, bias_p, bias_a, wtab);

    gemm_qkv<<<dim3(ROWS/128, NQKV/128), 256, 0, stream>>>(x_bf, w1_bf, cs_tab, Qb, Kb, Vt);
    attn_mfma<<<dim3(SEQ/64, NH, BATCH), 256, 0, stream>>>(Qb, Kb, Vt, wtab, attn_bf);
    gemm_out<<<dim3(ROWS/128, DMODEL/64), 256, 0, stream>>>(attn_bf, w2_bf, out, ROWS, DMODEL, DMODEL);
}

// Round 8
// 222.997 us; speedup vs baseline: 1.2804x; 1.1255x over previous
//
#include <hip/hip_runtime.h>
#include <math.h>

#define BATCH  2
#define SEQ    2048
#define DMODEL 1024
#define NH     16
#define HD     64
#define NQKV   3072
#define ROWS   (BATCH*SEQ)
#define NT     (SEQ/128)
#define QSCALE 0.18033688f   // 0.125 * log2(e): QK^T scores land in log2 domain

typedef unsigned short u16;
typedef unsigned int   u32;
typedef __bf16 bf16x8 __attribute__((ext_vector_type(8)));
typedef float  f32x4  __attribute__((ext_vector_type(4)));

typedef const __attribute__((address_space(1))) void* gptr_t;
typedef __attribute__((address_space(3))) void* lptr_t;

__device__ __forceinline__ void gload16(lptr_t l, const void* g) {
    __builtin_amdgcn_global_load_lds((gptr_t)g, l, 16, 0, 0);
}

__device__ __forceinline__ u16 f2bf(float f) {          // RNE f32->bf16
    unsigned int u = __float_as_uint(f);
    u += 0x7FFFu + ((u >> 16) & 1u);
    return (u16)(u >> 16);
}
__device__ __forceinline__ u32 pk2(float lo, float hi) { // pack 2 f32 -> 2 bf16
#if __has_builtin(__builtin_amdgcn_cvt_pk_bf16_f32)
    typedef __bf16 bf16x2 __attribute__((ext_vector_type(2)));
    union { bf16x2 v; u32 u; } cv;
    cv.v = __builtin_amdgcn_cvt_pk_bf16_f32(lo, hi);
    return cv.u;
#else
    return (u32)f2bf(lo) | ((u32)f2bf(hi) << 16);
#endif
}
__device__ __forceinline__ float fexp2(float x) {
#if __has_builtin(__builtin_amdgcn_exp2f)
    return __builtin_amdgcn_exp2f(x);
#else
    return exp2f(x);
#endif
}

// ---------------------------------------------------------------------------
// fused prep: f32->bf16 for x/qkv_w/out_w, rope cos/sin table, bias wtab.
// Blocks [0, NBC): convert; [NBC, NBC+256): rope table; [NBC+256, +128): wtab.
// ---------------------------------------------------------------------------
#define NBC ((ROWS*DMODEL + NQKV*DMODEL + DMODEL*DMODEL) / 1024)
__global__ void prep_kernel(const float* __restrict__ a,
                            const float* __restrict__ b,
                            const float* __restrict__ c,
                            u16* __restrict__ oa, u16* __restrict__ ob,
                            u16* __restrict__ oc,
                            const float* __restrict__ freqs, float* __restrict__ cs_tab,
                            const float* __restrict__ bias_p,
                            const float* __restrict__ bias_a,
                            float* __restrict__ wtab)
{
    const int na = ROWS*DMODEL, nb = NQKV*DMODEL;
    int blk = blockIdx.x;
    if (blk < NBC) {
        int i = (blk * 256 + threadIdx.x) * 4;
        const float* s; u16* d; int base;
        if (i < na)           { s = a; d = oa; base = i; }
        else if (i < na + nb) { s = b; d = ob; base = i - na; }
        else                  { s = c; d = oc; base = i - na - nb; }
        float4 v = *(const float4*)(s + base);
        u16 o[4] = { f2bf(v.x), f2bf(v.y), f2bf(v.z), f2bf(v.w) };
        *(uint2*)(d + base) = *(const uint2*)o;
    } else if (blk < NBC + 256) {
        int idx = (blk - NBC) * 256 + threadIdx.x;   // SEQ*32
        int s = idx >> 5, d = idx & 31;
        float sn, cs;
        sincosf((float)s * freqs[d], &sn, &cs);
        cs_tab[idx * 2]     = cs;
        cs_tab[idx * 2 + 1] = sn;
    } else {
        int idx = (blk - NBC - 256) * 256 + threadIdx.x;  // NH*SEQ
        int h = idx >> 11;
        int d = idx & (SEQ - 1);
        float p = fmaxf(bias_p[h], 0.01f);
        float aa = fmaxf(bias_a[h], 0.01f);
        wtab[idx] = __expf(-p * log1pf(aa * (float)d));
    }
}

// ---------------------------------------------------------------------------
// QKV GEMM with fused RoPE + layout epilogue (verified R6/R7). 128x128 tile.
// ---------------------------------------------------------------------------
__global__ __launch_bounds__(256) void gemm_qkv(
    const u16* __restrict__ A, const u16* __restrict__ B,
    const float* __restrict__ cs_tab,
    u16* __restrict__ Qb, u16* __restrict__ Kb, u16* __restrict__ Vt)
{
    const int K = DMODEL;
    __shared__ __align__(16) u16 As[128][32];
    __shared__ __align__(16) u16 Bs[128][32];
    const int tid  = threadIdx.x;
    const int wave = tid >> 6, lane = tid & 63;
    const int quad = lane >> 4, l16 = lane & 15;
    const int wrow = (wave >> 1) * 64, wcol = (wave & 1) * 64;
    const int bm = blockIdx.x * 128, bn = blockIdx.y * 128;

    const int srow = lane >> 2;                       // 0..15
    const int scol = ((lane & 3) ^ (srow & 3)) * 8;   // swizzled chunk (u16)
    const int fsw = (quad ^ (l16 & 3)) * 8;           // frag read swizzle

    f32x4 acc[4][4];
#pragma unroll
    for (int i = 0; i < 4; ++i)
#pragma unroll
        for (int j = 0; j < 4; ++j) acc[i][j] = (f32x4){0.f,0.f,0.f,0.f};

    const u16* Ag0 = A + (size_t)(bm + wave*32 + srow)      * K + scol;
    const u16* Ag1 = A + (size_t)(bm + wave*32 + 16 + srow) * K + scol;
    const u16* Bg0 = B + (size_t)(bn + wave*32 + srow)      * K + scol;
    const u16* Bg1 = B + (size_t)(bn + wave*32 + 16 + srow) * K + scol;

    for (int k0 = 0; k0 < K; k0 += 32) {
        __syncthreads();
        gload16((lptr_t)&As[wave*32][0],      Ag0 + k0);
        gload16((lptr_t)&As[wave*32 + 16][0], Ag1 + k0);
        gload16((lptr_t)&Bs[wave*32][0],      Bg0 + k0);
        gload16((lptr_t)&Bs[wave*32 + 16][0], Bg1 + k0);
        __syncthreads();
        bf16x8 af[4], bfr[4];
#pragma unroll
        for (int i = 0; i < 4; ++i)
            af[i] = *(const bf16x8*)&As[wrow + i*16 + l16][fsw];
#pragma unroll
        for (int j = 0; j < 4; ++j)
            bfr[j] = *(const bf16x8*)&Bs[wcol + j*16 + l16][fsw];
#pragma unroll
        for (int i = 0; i < 4; ++i)
#pragma unroll
            for (int j = 0; j < 4; ++j)
                acc[i][j] = __builtin_amdgcn_mfma_f32_16x16x32_bf16(af[i], bfr[j], acc[i][j], 0, 0, 0);
    }

    // ---- fused epilogue ----
    const int tcol = (bn + wcol) >> 6;          // global 64-col index, 0..47
    const int t = tcol >> 4, h = tcol & 15;     // tensor (q/k/v), head
    const int bq = bm >> 11;                    // batch (tile never crosses)
    const int sb = (bm & (SEQ - 1)) + wrow;     // s base of this quadrant
    const size_t hb = (size_t)(bq * NH + h) * SEQ * HD;

    if (t == 2) {
#pragma unroll
        for (int i = 0; i < 4; ++i) {
            const int s = sb + i*16 + quad*4;
#pragma unroll
            for (int j = 0; j < 4; ++j) {
                const int d = j*16 + l16;
                uint2 pv = make_uint2(pk2(acc[i][j][0], acc[i][j][1]),
                                      pk2(acc[i][j][2], acc[i][j][3]));
                *(uint2*)&Vt[hb + (size_t)d * SEQ + s] = pv;
            }
        }
    } else {
        const float sc = (t == 0) ? QSCALE : 1.0f;
        u16* dstb = ((t == 0) ? Qb : Kb) + hb;
#pragma unroll
        for (int i = 0; i < 4; ++i) {
#pragma unroll
            for (int r = 0; r < 4; ++r) {
                const int s = sb + i*16 + quad*4 + r;
                const float2* ct = (const float2*)(cs_tab + ((size_t)s * 32 + l16) * 2);
                float2 cs0 = ct[0];     // freq idx l16
                float2 cs1 = ct[16];    // freq idx l16+16
                float a0 = acc[i][0][r], a1 = acc[i][1][r];
                float a2 = acc[i][2][r], a3 = acc[i][3][r];
                u16* dst = dstb + (size_t)s * HD;
                dst[l16]      = f2bf((a0*cs0.x - a2*cs0.y) * sc);
                dst[16 + l16] = f2bf((a1*cs1.x - a3*cs1.y) * sc);
                dst[32 + l16] = f2bf((a0*cs0.y + a2*cs0.x) * sc);
                dst[48 + l16] = f2bf((a1*cs1.y + a3*cs1.x) * sc);
            }
        }
    }
}

// ---------------------------------------------------------------------------
// out-projection GEMM: 128x64 tile (M x N) -> 512 blocks = 2+/CU for overlap.
// Wave w: rows (w>>1)*64, cols (w&1)*32. LDS 12 KB.
// ---------------------------------------------------------------------------
__global__ __launch_bounds__(256) void gemm_out(
    const u16* __restrict__ A, const u16* __restrict__ B,
    float* __restrict__ Cout, int M, int N, int K)
{
    __shared__ __align__(16) u16 As[128][32];
    __shared__ __align__(16) u16 Bs[64][32];
    const int tid  = threadIdx.x;
    const int wave = tid >> 6, lane = tid & 63;
    const int quad = lane >> 4, l16 = lane & 15;
    const int wrow = (wave >> 1) * 64, wcol = (wave & 1) * 32;
    const int bm = blockIdx.x * 128, bn = blockIdx.y * 64;

    const int srow = lane >> 2;
    const int scol = ((lane & 3) ^ (srow & 3)) * 8;
    const int fsw = (quad ^ (l16 & 3)) * 8;

    f32x4 acc[4][2];
#pragma unroll
    for (int i = 0; i < 4; ++i)
#pragma unroll
        for (int j = 0; j < 2; ++j) acc[i][j] = (f32x4){0.f,0.f,0.f,0.f};

    const u16* Ag0 = A + (size_t)(bm + wave*32 + srow)      * K + scol;
    const u16* Ag1 = A + (size_t)(bm + wave*32 + 16 + srow) * K + scol;
    const u16* Bg0 = B + (size_t)(bn + wave*16 + srow)      * K + scol;

    for (int k0 = 0; k0 < K; k0 += 32) {
        __syncthreads();
        gload16((lptr_t)&As[wave*32][0],      Ag0 + k0);
        gload16((lptr_t)&As[wave*32 + 16][0], Ag1 + k0);
        gload16((lptr_t)&Bs[wave*16][0],      Bg0 + k0);
        __syncthreads();
        bf16x8 af[4], bfr[2];
#pragma unroll
        for (int i = 0; i < 4; ++i)
            af[i] = *(const bf16x8*)&As[wrow + i*16 + l16][fsw];
#pragma unroll
        for (int j = 0; j < 2; ++j)
            bfr[j] = *(const bf16x8*)&Bs[wcol + j*16 + l16][fsw];
#pragma unroll
        for (int i = 0; i < 4; ++i)
#pragma unroll
            for (int j = 0; j < 2; ++j)
                acc[i][j] = __builtin_amdgcn_mfma_f32_16x16x32_bf16(af[i], bfr[j], acc[i][j], 0, 0, 0);
    }

#pragma unroll
    for (int i = 0; i < 4; ++i)
#pragma unroll
        for (int j = 0; j < 2; ++j) {
            int col = bn + wcol + j*16 + l16;
#pragma unroll
            for (int r = 0; r < 4; ++r) {
                int row = bm + wrow + i*16 + quad*4 + r;
                Cout[(size_t)row * N + col] = acc[i][j][r];
            }
        }
}

// ---------------------------------------------------------------------------
// MFMA flash attention v13: v8 skeleton, re-phased so every vmcnt wait is
// covered (hipcc drains vmcnt(0) at every __syncthreads):
//  - ALL vmem issue moves to just after b1: kf global loads FIRST, then the
//    V DMA (in-order vmcnt -> kf wait leaves the DMA in flight; region is
//    barrier-free so the compiler emits counted waits).
//  - softmax fused per (kg,qj) and moved BEFORE the Vs-ready barrier: legal
//    because ws2 is double-buffered, staged one tile ahead during PV (where
//    its wh-load vmcnt(0) is harmless - DMA already drained).
//  - b2+b3 merge: ONE barrier publishes both Vs and Ps -> 2 barriers/tile,
//    V-DMA covered by QK+softmax (~500+ cy) instead of ~160.
//  Vs stays single-buffered. LDS = 16K Ps + 16K Vs + 1.5K ws2 + 1.25K misc
//  = 35584 -> 4 blocks/CU. Numerics identical to v8.
// ---------------------------------------------------------------------------
__global__ __launch_bounds__(256, 4) void attn_mfma(
    const u16* __restrict__ Qb, const u16* __restrict__ Kb,
    const u16* __restrict__ Vt, const float* __restrict__ wtab,
    u16* __restrict__ attn_bf)
{
    __shared__ __align__(16) u16 Ps[4*64*32];  // [keygroup][q][key^psw]
    __shared__ __align__(16) u16 Vs[64*128];   // [d][key], 16-chunk rows, swizzled
    __shared__ u32 ws2[2][192];                // packed {w[m], w[m+1]}, dbuf
    __shared__ float lred[4][64];
    __shared__ float linv[64];

    const int tid = threadIdx.x;
    const int wave = tid >> 6, lane = tid & 63;
    const int quad = lane >> 4, l16 = lane & 15;
    const int q0 = blockIdx.x * 64, h = blockIdx.y, b = blockIdx.z;

    const u16* Qh = Qb + (size_t)(b * NH + h) * SEQ * HD;
    const u16* Kh = Kb + (size_t)(b * NH + h) * SEQ * HD;
    const u16* Vh = Vt + (size_t)(b * NH + h) * HD * SEQ;
    const float* wh = wtab + h * SEQ;

    // Q fragments (B-operand of S^T): all 64 q rows per wave, in registers
    bf16x8 qf0[4], qf1[4];
#pragma unroll
    for (int qj = 0; qj < 4; ++qj) {
        const u16* qr = Qh + (size_t)(q0 + qj*16 + l16) * HD + quad * 8;
        qf0[qj] = *(const bf16x8*)qr;
        qf1[qj] = *(const bf16x8*)(qr + 32);
    }

    // K fragment base: this wave's keys, direct fragment layout
    const u16* Kf0 = Kh + (size_t)(wave*32 + l16) * HD + quad * 8;

    // V staging source: 4 issues, 4 rows x 16 chunks each; chunk' = chunk ^ (d&7)
    const int vsrow = lane >> 4;                       // 0..3
    const u16* Vst[4];
#pragma unroll
    for (int i = 0; i < 4; ++i) {
        int d = wave*16 + i*4 + vsrow;
        int vscol = ((lane & 15) ^ (d & 7)) * 8;
        Vst[i] = Vh + (size_t)d * SEQ + vscol;
    }

    const int psw  = ((l16 >> 1) & 3) << 3;            // P swizzle: row-keyed, 8-granular
    const int mb0  = 127 + l16 - wave*32 - quad*4 - 3; // w-window base (>=0)

    float l_p[4] = {0.f, 0.f, 0.f, 0.f};
    f32x4 o[4];
#pragma unroll
    for (int j = 0; j < 4; ++j) o[j] = (f32x4){0.f,0.f,0.f,0.f};

    // ---- prologue: bias window for tile 0 (visible after loop-top b1) ----
    if (tid < 192) {
        int i0 = (q0 - 127) + tid;
        int a0 = i0 < 0 ? -i0 : i0;  if (a0 > SEQ-1) a0 = SEQ-1;
        int i1 = i0 + 1;
        int a1 = i1 < 0 ? -i1 : i1;  if (a1 > SEQ-1) a1 = SEQ-1;
        ws2[0][tid] = pk2(wh[a0], wh[a1]);
    }

    for (int kt = 0; kt < NT; ++kt) {
        const int k0 = kt * 128;
        const int cur = kt & 1;
        const u32* wsb = ws2[cur];

        __syncthreads();   // b1: PV(t-1) Ps/Vs reads done; ws2[cur] visible

        // ---- kf loads FIRST (their wait = vmcnt(4), DMA stays in flight) ----
        bf16x8 kf[2][2];
#pragma unroll
        for (int kg = 0; kg < 2; ++kg) {
            const u16* kp = Kf0 + (size_t)(k0 + kg*16) * HD;
            kf[kg][0] = *(const bf16x8*)kp;
            kf[kg][1] = *(const bf16x8*)(kp + 32);
        }
        __builtin_amdgcn_sched_barrier(0);  // pin: kf issue stays above DMA

        // ---- V DMA for THIS tile (drained at B, covered by QK+softmax) ----
#pragma unroll
        for (int i = 0; i < 4; ++i)
            gload16((lptr_t)&Vs[(wave*16 + i*4)*128], Vst[i] + k0);

        // ---- fused QK + softmax + P write, per (kg,qj) ----
#pragma unroll
        for (int kg = 0; kg < 2; ++kg) {
#pragma unroll
            for (int qj = 0; qj < 4; ++qj) {
                f32x4 zz = (f32x4){0.f,0.f,0.f,0.f};
                zz = __builtin_amdgcn_mfma_f32_16x16x32_bf16(kf[kg][0], qf0[qj], zz, 0, 0, 0);
                zz = __builtin_amdgcn_mfma_f32_16x16x32_bf16(kf[kg][1], qf1[qj], zz, 0, 0, 0);
                const int mbase = mb0 + qj*16 - kg*16;
                u32 pA = wsb[mbase], pB = wsb[mbase + 2];
                float w3 = __uint_as_float(pA << 16);
                float w2 = __uint_as_float(pA & 0xffff0000u);
                float w1 = __uint_as_float(pB << 16);
                float w0 = __uint_as_float(pB & 0xffff0000u);
                float e0 = fexp2(zz[0]) * w0, e1 = fexp2(zz[1]) * w1;
                float e2 = fexp2(zz[2]) * w2, e3 = fexp2(zz[3]) * w3;
                l_p[qj] += (e0 + e1) + (e2 + e3);
                *(uint2*)&Ps[wave*2048 + (qj*16 + l16)*32
                             + ((kg*16 + quad*4) ^ psw)] =
                    make_uint2(pk2(e0, e1), pk2(e2, e3));
            }
        }

        __syncthreads();   // B: Vs ready (DMA drained) AND Ps visible

        // ---- PV: O[q=wave rows][d] += P * V over 128 keys ----
        bf16x8 pf[4];
#pragma unroll
        for (int m = 0; m < 4; ++m)
            pf[m] = *(const bf16x8*)&Ps[m*2048 + (wave*16 + l16)*32
                                        + ((quad*8) ^ psw)];
#pragma unroll
        for (int j = 0; j < 4; ++j) {
            const int vrow = (j*16 + l16) * 128;
            const int vsw = l16 & 7;
#pragma unroll
            for (int m = 0; m < 4; ++m) {
                bf16x8 vf = *(const bf16x8*)&Vs[vrow + (((m*4 + quad) ^ vsw) * 8)];
                o[j] = __builtin_amdgcn_mfma_f32_16x16x32_bf16(pf[m], vf, o[j], 0, 0, 0);
            }
        }

        // ---- stage ws2 for t+1 (vmcnt(0) here is free: DMA already drained)
        if (kt + 1 < NT && tid < 192) {
            int i0 = (q0 - (k0 + 128) - 127) + tid;
            int a0 = i0 < 0 ? -i0 : i0;  if (a0 > SEQ-1) a0 = SEQ-1;
            int i1 = i0 + 1;
            int a1 = i1 < 0 ? -i1 : i1;  if (a1 > SEQ-1) a1 = SEQ-1;
            ws2[cur ^ 1][tid] = pk2(wh[a0], wh[a1]);
        }
    }

    // ---- epilogue: reduce l (quads via shfl, waves via LDS), store ----
    __syncthreads();
#pragma unroll
    for (int qj = 0; qj < 4; ++qj) {
        float l = l_p[qj];
        l += __shfl_xor(l, 16);
        l += __shfl_xor(l, 32);
        if (quad == 0) lred[wave][qj*16 + l16] = l;
    }
    __syncthreads();
    if (tid < 64)
        linv[tid] = 1.0f / (lred[0][tid] + lred[1][tid] + lred[2][tid] + lred[3][tid]);
    __syncthreads();
#pragma unroll
    for (int r = 0; r < 4; ++r) {
        const int q = wave*16 + quad*4 + r;
        float inv = linv[q];
        u16* dst = attn_bf + (size_t)(b * SEQ + q0 + q) * DMODEL + h * HD;
#pragma unroll
        for (int j = 0; j < 4; ++j)
            dst[j*16 + l16] = f2bf(o[j][r] * inv);
    }
}

// ---------------------------------------------------------------------------
extern "C" void kernel_launch(void* const* d_in, const int* in_sizes, int n_in,
                              void* d_out, int out_size, void* d_ws, size_t ws_size,
                              hipStream_t stream)
{
    (void)in_sizes; (void)n_in; (void)out_size; (void)ws_size;
    const float* x      = (const float*)d_in[0];
    const float* qkv_w  = (const float*)d_in[1];
    const float* out_w  = (const float*)d_in[2];
    const float* bias_p = (const float*)d_in[3];
    const float* bias_a = (const float*)d_in[4];
    const float* freqs  = (const float*)d_in[5];
    float* out = (float*)d_out;

    // ws layout (bytes):
    //   [0, 8M)       attn_bf [4096][1024] bf16
    //   [8M, 16M)     Qb      [2][16][2048][64] bf16
    //   [24M, 32M)    x_bf    [4096][1024] bf16
    //   [32M, 38M)    w1_bf   [3072][1024] bf16
    //   [38M, 40M)    w2_bf   [1024][1024] bf16
    //   [40M, 48M)    Kb      [2][16][2048][64] bf16
    //   [48M, 56M)    Vt      [2][16][64][2048] bf16
    //   [56M, +128K)  wtab    [16][2048] f32 (exp of bias)
    //   [+128K,+640K) cs_tab  [2048][32][2] f32
    char* ws = (char*)d_ws;
    u16*   attn_bf = (u16*)ws;
    u16*   Qb      = (u16*)(ws + 8388608);
    u16*   x_bf    = (u16*)(ws + 25165824);
    u16*   w1_bf   = (u16*)(ws + 33554432);
    u16*   w2_bf   = (u16*)(ws + 39845888);
    u16*   Kb      = (u16*)(ws + 41943040);
    u16*   Vt      = (u16*)(ws + 50331648);
    float* wtab    = (float*)(ws + 58720256);
    float* cs_tab  = (float*)(ws + 58720256 + 131072);

    prep_kernel<<<dim3(NBC + 256 + 128), 256, 0, stream>>>(
        x, qkv_w, out_w, x_bf, w1_bf, w2_bf, freqs, cs_tab, bias_p, bias_a, wtab);

    gemm_qkv<<<dim3(ROWS/128, NQKV/128), 256, 0, stream>>>(x_bf, w1_bf, cs_tab, Qb, Kb, Vt);
    attn_mfma<<<dim3(SEQ/64, NH, BATCH), 256, 0, stream>>>(Qb, Kb, Vt, wtab, attn_bf);
    gemm_out<<<dim3(ROWS/128, DMODEL/64), 256, 0, stream>>>(attn_bf, w2_bf, out, ROWS, DMODEL, DMODEL);
}